// Round 2
// baseline (214.830 us; speedup 1.0000x reference)
//
#include <hip/hip_runtime.h>
#include <hip/hip_bf16.h>
#include <stdint.h>

// Problem constants: B=2, S=2048, D=1024, H=16, DH=64, M = B*S = 4096.

typedef __attribute__((ext_vector_type(8))) short bf16x8;
typedef __attribute__((ext_vector_type(4))) float f32x4;

__device__ __forceinline__ void gld16(const void* g, void* l) {
  __builtin_amdgcn_global_load_lds((const __attribute__((address_space(1))) void*)g,
                                   (__attribute__((address_space(3))) void*)l, 16, 0, 0);
}

__device__ __forceinline__ unsigned short f2b(float f) {
  __hip_bfloat16 h = __float2bfloat16(f);
  return *reinterpret_cast<unsigned short*>(&h);
}

// ---------------- prep: x fp32->bf16 (blocks 0..4095) + W transpose (4096..5119) ----------------
__global__ __launch_bounds__(256) void prep_kernel(const float* __restrict__ x,
                                                   const float* __restrict__ Wq,
                                                   const float* __restrict__ Wk,
                                                   const float* __restrict__ Wv,
                                                   const float* __restrict__ Wo,
                                                   unsigned short* __restrict__ xb,
                                                   unsigned short* __restrict__ wt) {
  __shared__ unsigned short Ls[64 * 72];
  int bid = blockIdx.x;
  int t = threadIdx.x;
  if (bid < 4096) {
    int i = (bid * 256 + t) * 4;
    float4 v = *(const float4*)(x + i);
    ushort4 o = make_ushort4(f2b(v.x), f2b(v.y), f2b(v.z), f2b(v.w));
    *(ushort4*)(xb + i) = o;
    return;
  }
  int tid = bid - 4096;
  int z = tid >> 8, rem = tid & 255;
  int bx = rem & 15, by = rem >> 4;
  const float* src = (z == 0) ? Wq : (z == 1) ? Wk : (z == 2) ? Wv : Wo;
  unsigned short* dst = wt + (size_t)z * 1024 * 1024;
  int k0 = bx * 64, n0 = by * 64;
  int c4 = t & 15;
#pragma unroll
  for (int it = 0; it < 4; ++it) {
    int row = it * 16 + (t >> 4);
    float4 v = *(const float4*)(src + (k0 + row) * 1024 + n0 + c4 * 4);
    Ls[(c4 * 4 + 0) * 72 + row] = f2b(v.x);
    Ls[(c4 * 4 + 1) * 72 + row] = f2b(v.y);
    Ls[(c4 * 4 + 2) * 72 + row] = f2b(v.z);
    Ls[(c4 * 4 + 3) * 72 + row] = f2b(v.w);
  }
  __syncthreads();
  int nr = t >> 2, kc = (t & 3) * 16;
  *(uint4*)(dst + (size_t)(n0 + nr) * 1024 + k0 + kc) = *(uint4*)&Ls[nr * 72 + kc];
  *(uint4*)(dst + (size_t)(n0 + nr) * 1024 + k0 + kc + 8) = *(uint4*)&Ls[nr * 72 + kc + 8];
}

// ---------------- fused QKV GEMM ----------------
// Round-5: prefetch double-buffer (T3 minimum 2-phase). STAGE(kt+1) is issued
// BEFORE the ds_read+MFMA of tile kt, so the global->LDS latency hides under
// compute; one barrier per K-step instead of two.
// Q is pre-scaled by 0.125*log2(e) so attention can use raw exp2.
__global__ __launch_bounds__(256) void gemm_qkv(const unsigned short* __restrict__ Ab,
                                                const unsigned short* __restrict__ Bt,
                                                const float* __restrict__ bq,
                                                const float* __restrict__ bk,
                                                const float* __restrict__ bv,
                                                unsigned short* __restrict__ qb,
                                                unsigned short* __restrict__ kb,
                                                unsigned short* __restrict__ vtb) {
  __shared__ unsigned short As[2][128 * 32];
  __shared__ unsigned short Bs[2][128 * 32];
  __shared__ unsigned short Es[128 * 72];  // also viewed as [64][136] for V (9216 >= 8704)
  const int t = threadIdx.x;
  const int lane = t & 63, wave = t >> 6;
  const int m0 = blockIdx.x * 128, n0 = blockIdx.y * 128;
  const int wr = (wave >> 1) * 64, wc = (wave & 1) * 64;
  const int fr = lane & 15, fq = lane >> 4;
  const int srow = t >> 2, scol = (t & 3) * 8;
  f32x4 acc[4][4] = {};

  {  // prologue: stage kt=0 into buf 0
    const unsigned short* Ag = Ab + (size_t)m0 * 1024;
    const unsigned short* Bg = Bt + (size_t)n0 * 1024;
#pragma unroll
    for (int rep = 0; rep < 2; ++rep) {
      int c = t + rep * 256;
      int row = c >> 2, col = (c & 3) * 8;
      gld16(Ag + (size_t)row * 1024 + col, (void*)(As[0] + c * 8));
      gld16(Bg + (size_t)row * 1024 + col, (void*)(Bs[0] + c * 8));
    }
  }
  __syncthreads();

  int buf = 0;
  for (int kt = 0; kt < 32; ++kt) {
    if (kt + 1 < 32) {  // prefetch next tile into other buffer
      const unsigned short* Ag = Ab + (size_t)m0 * 1024 + (kt + 1) * 32;
      const unsigned short* Bg = Bt + (size_t)n0 * 1024 + (kt + 1) * 32;
#pragma unroll
      for (int rep = 0; rep < 2; ++rep) {
        int c = t + rep * 256;
        int row = c >> 2, col = (c & 3) * 8;
        gld16(Ag + (size_t)row * 1024 + col, (void*)(As[buf ^ 1] + c * 8));
        gld16(Bg + (size_t)row * 1024 + col, (void*)(Bs[buf ^ 1] + c * 8));
      }
    }
    bf16x8 a[4], b[4];
#pragma unroll
    for (int i = 0; i < 4; ++i) a[i] = *(const bf16x8*)&As[buf][(wr + i * 16 + fr) * 32 + fq * 8];
#pragma unroll
    for (int j = 0; j < 4; ++j) b[j] = *(const bf16x8*)&Bs[buf][(wc + j * 16 + fr) * 32 + fq * 8];
#pragma unroll
    for (int i = 0; i < 4; ++i)
#pragma unroll
      for (int j = 0; j < 4; ++j)
        acc[i][j] = __builtin_amdgcn_mfma_f32_16x16x32_bf16(a[i], b[j], acc[i][j], 0, 0, 0);
    __syncthreads();  // drains prefetch (vmcnt) + all waves done with buf
    buf ^= 1;
  }
  const int which = n0 >> 10;  // 0=q, 1=k, 2=v (uniform per block)
  const int bidx = m0 >> 11, s0 = m0 & 2047;
  if (which == 2) {
    // V: Es as [dh_l][136] (s-contig rows), b64 LDS writes, 256-B coalesced global rows.
#pragma unroll
    for (int nh = 0; nh < 2; ++nh) {
      if ((wc >> 6) == nh) {
#pragma unroll
        for (int j = 0; j < 4; ++j) {
          int col = j * 16 + fr;  // dh_l 0..63
          float bias = bv[(n0 + nh * 64 + col) & 1023];
#pragma unroll
          for (int i = 0; i < 4; ++i) {
            int sl = wr + i * 16 + fq * 4;
            ushort4 pk;
            pk.x = f2b(acc[i][j][0] + bias);
            pk.y = f2b(acc[i][j][1] + bias);
            pk.z = f2b(acc[i][j][2] + bias);
            pk.w = f2b(acc[i][j][3] + bias);
            *(uint2*)&Es[col * 136 + sl] = *(uint2*)&pk;
          }
        }
      }
      __syncthreads();
      int h = ((n0 + nh * 64) & 1023) >> 6;
#pragma unroll
      for (int it = 0; it < 4; ++it) {
        int dh = it * 16 + (t >> 4);
        int ck = (t & 15) * 8;
        uint4 vv = *(uint4*)&Es[dh * 136 + ck];
        *(uint4*)&vtb[(size_t)((bidx * 16 + h) * 64 + dh) * 2048 + s0 + ck] = vv;
      }
      __syncthreads();
    }
  } else {
    unsigned short* dst = (which == 0) ? qb : kb;
    const float* bias_p = (which == 0) ? bq : bk;
    float scale = (which == 0) ? 0.1803368801111204f : 1.0f;
#pragma unroll
    for (int nh = 0; nh < 2; ++nh) {
      if ((wc >> 6) == nh) {
#pragma unroll
        for (int j = 0; j < 4; ++j) {
          int col = j * 16 + fr;
          float bias = bias_p[(n0 + nh * 64 + col) & 1023];
#pragma unroll
          for (int i = 0; i < 4; ++i)
#pragma unroll
            for (int r = 0; r < 4; ++r) {
              int sl = wr + i * 16 + fq * 4 + r;
              Es[sl * 72 + col] = f2b((acc[i][j][r] + bias) * scale);
            }
        }
      }
      __syncthreads();
      int h = ((n0 + nh * 64) & 1023) >> 6;
#pragma unroll
      for (int it = 0; it < 4; ++it) {
        int sl = it * 32 + (t >> 3);
        int ck = (t & 7) * 8;
        uint4 vv = *(uint4*)&Es[sl * 72 + ck];
        *(uint4*)&dst[(size_t)((bidx * 16 + h) * 2048 + s0 + sl) * 64 + ck] = vv;
      }
      __syncthreads();
    }
  }
}

// ---------------- flash attention (unchanged from round 4) ----------------
__global__ __launch_bounds__(256, 2) void attn_kernel(const unsigned short* __restrict__ qb,
                                                      const unsigned short* __restrict__ kb,
                                                      const unsigned short* __restrict__ vtb,
                                                      unsigned short* __restrict__ attn) {
  __shared__ unsigned short Ks[2 * 4096];
  __shared__ unsigned short Vs[2 * 4096];
  __shared__ unsigned short Ps[4 * 2048];
  const int t = threadIdx.x, lane = t & 63, w = t >> 6;
  const int fr = lane & 15, fq = lane >> 4;
  const int rid = blockIdx.y * 16 + blockIdx.x;
  const int bh = (rid & 7) + ((rid >> 7) << 3);
  const int q0 = ((rid >> 3) & 15) * 128;
  const int ksel = (fq ^ ((fr >> 1) & 3)) * 8;
  const unsigned short* qg = qb + (size_t)bh * 2048 * 64;
  const unsigned short* kg0 = kb + (size_t)bh * 2048 * 64;
  const unsigned short* vg0 = vtb + (size_t)bh * 64 * 2048;

  bf16x8 qf[2][2];
#pragma unroll
  for (int nb = 0; nb < 2; ++nb)
#pragma unroll
    for (int kk = 0; kk < 2; ++kk)
      qf[nb][kk] = *(const bf16x8*)(qg + (size_t)(q0 + w * 32 + nb * 16 + fr) * 64 + kk * 32 + fq * 8);

  bf16x8 ones;
#pragma unroll
  for (int i = 0; i < 8; ++i) ones[i] = (short)0x3F80;

  f32x4 oacc[2][4] = {};
  f32x4 lacc[2] = {};
  unsigned short* Pw = Ps + w * 2048;

  {
#pragma unroll
    for (int rep = 0; rep < 2; ++rep) {
      int c = t + rep * 256;
      int kk = c >> 8, row = (c >> 2) & 63, cc = c & 3;
      int cs = cc ^ ((row >> 1) & 3);  // pre-swizzle global source chunk
      gld16(kg0 + row * 64 + kk * 32 + cs * 8, (void*)(Ks + c * 8));
      gld16(vg0 + (size_t)row * 2048 + kk * 32 + cs * 8, (void*)(Vs + c * 8));
    }
  }

  for (int kt = 0; kt < 32; ++kt) {
    int buf = kt & 1;
    __syncthreads();
    if (kt + 1 < 32) {
      const unsigned short* kg = kg0 + (size_t)(kt + 1) * 4096;
      const unsigned short* vg = vg0 + (kt + 1) * 64;
      int lb = (buf ^ 1) * 4096;
#pragma unroll
      for (int rep = 0; rep < 2; ++rep) {
        int c = t + rep * 256;
        int kk = c >> 8, row = (c >> 2) & 63, cc = c & 3;
        int cs = cc ^ ((row >> 1) & 3);
        gld16(kg + row * 64 + kk * 32 + cs * 8, (void*)(Ks + lb + c * 8));
        gld16(vg + (size_t)row * 2048 + kk * 32 + cs * 8, (void*)(Vs + lb + c * 8));
      }
    }
    const unsigned short* Kb = Ks + buf * 4096;
    const unsigned short* Vb = Vs + buf * 4096;
    f32x4 sacc[4][2] = {};
#pragma unroll
    for (int kk = 0; kk < 2; ++kk) {
      bf16x8 kf[4];
#pragma unroll
      for (int m = 0; m < 4; ++m) kf[m] = *(const bf16x8*)&Kb[kk * 2048 + (m * 16 + fr) * 32 + ksel];
      __builtin_amdgcn_s_setprio(1);
#pragma unroll
      for (int m = 0; m < 4; ++m)
#pragma unroll
        for (int nb = 0; nb < 2; ++nb)
          sacc[m][nb] = __builtin_amdgcn_mfma_f32_16x16x32_bf16(kf[m], qf[nb][kk], sacc[m][nb], 0, 0, 0);
      __builtin_amdgcn_s_setprio(0);
    }
#pragma unroll
    for (int m = 0; m < 4; ++m)
#pragma unroll
      for (int nb = 0; nb < 2; ++nb) {
        int qw = nb * 16 + fr;
        int G = (m * 2 + (fq >> 1)) ^ (qw & 7);
        ushort4 pk;
        pk.x = f2b(__builtin_amdgcn_exp2f(sacc[m][nb][0]));
        pk.y = f2b(__builtin_amdgcn_exp2f(sacc[m][nb][1]));
        pk.z = f2b(__builtin_amdgcn_exp2f(sacc[m][nb][2]));
        pk.w = f2b(__builtin_amdgcn_exp2f(sacc[m][nb][3]));
        *(uint2*)&Pw[qw * 64 + G * 8 + (fq & 1) * 4] = *(uint2*)&pk;
      }
#pragma unroll
    for (int kk = 0; kk < 2; ++kk) {
      bf16x8 pf[2];
#pragma unroll
      for (int mb = 0; mb < 2; ++mb) {
        int qw = mb * 16 + fr;
        int G = (kk * 4 + fq) ^ (qw & 7);
        pf[mb] = *(const bf16x8*)&Pw[qw * 64 + G * 8];
      }
      __builtin_amdgcn_s_setprio(1);
#pragma unroll
      for (int n = 0; n < 4; ++n) {
        bf16x8 vf = *(const bf16x8*)&Vb[kk * 2048 + (n * 16 + fr) * 32 + ksel];
#pragma unroll
        for (int mb = 0; mb < 2; ++mb)
          oacc[mb][n] = __builtin_amdgcn_mfma_f32_16x16x32_bf16(pf[mb], vf, oacc[mb][n], 0, 0, 0);
      }
#pragma unroll
      for (int mb = 0; mb < 2; ++mb)
        lacc[mb] = __builtin_amdgcn_mfma_f32_16x16x32_bf16(pf[mb], ones, lacc[mb], 0, 0, 0);
      __builtin_amdgcn_s_setprio(0);
    }
  }
  int bidx = bh >> 4, h = bh & 15;
#pragma unroll
  for (int mb = 0; mb < 2; ++mb)
#pragma unroll
    for (int r = 0; r < 4; ++r) {
      float inv = 1.f / lacc[mb][r];
      int s = q0 + w * 32 + mb * 16 + fq * 4 + r;
      size_t base = (size_t)(bidx * 2048 + s) * 1024 + h * 64;
#pragma unroll
      for (int n = 0; n < 4; ++n) attn[base + n * 16 + fr] = f2b(oacc[mb][n][r] * inv);
    }
}

// ---------------- output projection ----------------
// Round-5: same prefetch double-buffer restructure. This kernel runs at
// 1 block/CU (grid 256), so without prefetch every K-step paid the full
// global->LDS latency serially.
__global__ __launch_bounds__(256) void gemm_out(const unsigned short* __restrict__ Ab,
                                                const unsigned short* __restrict__ Bt,
                                                const float* __restrict__ bo,
                                                float* __restrict__ out) {
  __shared__ unsigned short As[2][128 * 32];
  __shared__ unsigned short Bs[2][128 * 32];
  const int t = threadIdx.x;
  const int lane = t & 63, wave = t >> 6;
  const int m0 = blockIdx.x * 128, n0 = blockIdx.y * 128;
  const int wr = (wave >> 1) * 64, wc = (wave & 1) * 64;
  const int fr = lane & 15, fq = lane >> 4;
  f32x4 acc[4][4] = {};

  {
    const unsigned short* Ag = Ab + (size_t)m0 * 1024;
    const unsigned short* Bg = Bt + (size_t)n0 * 1024;
#pragma unroll
    for (int rep = 0; rep < 2; ++rep) {
      int c = t + rep * 256;
      int row = c >> 2, col = (c & 3) * 8;
      gld16(Ag + (size_t)row * 1024 + col, (void*)(As[0] + c * 8));
      gld16(Bg + (size_t)row * 1024 + col, (void*)(Bs[0] + c * 8));
    }
  }
  __syncthreads();

  int buf = 0;
  for (int kt = 0; kt < 32; ++kt) {
    if (kt + 1 < 32) {
      const unsigned short* Ag = Ab + (size_t)m0 * 1024 + (kt + 1) * 32;
      const unsigned short* Bg = Bt + (size_t)n0 * 1024 + (kt + 1) * 32;
#pragma unroll
      for (int rep = 0; rep < 2; ++rep) {
        int c = t + rep * 256;
        int row = c >> 2, col = (c & 3) * 8;
        gld16(Ag + (size_t)row * 1024 + col, (void*)(As[buf ^ 1] + c * 8));
        gld16(Bg + (size_t)row * 1024 + col, (void*)(Bs[buf ^ 1] + c * 8));
      }
    }
    bf16x8 a[4], b[4];
#pragma unroll
    for (int i = 0; i < 4; ++i) a[i] = *(const bf16x8*)&As[buf][(wr + i * 16 + fr) * 32 + fq * 8];
#pragma unroll
    for (int j = 0; j < 4; ++j) b[j] = *(const bf16x8*)&Bs[buf][(wc + j * 16 + fr) * 32 + fq * 8];
#pragma unroll
    for (int i = 0; i < 4; ++i)
#pragma unroll
      for (int j = 0; j < 4; ++j)
        acc[i][j] = __builtin_amdgcn_mfma_f32_16x16x32_bf16(a[i], b[j], acc[i][j], 0, 0, 0);
    __syncthreads();
    buf ^= 1;
  }
#pragma unroll
  for (int j = 0; j < 4; ++j) {
    int gn = n0 + wc + j * 16 + fr;
    float bias = bo[gn];
#pragma unroll
    for (int i = 0; i < 4; ++i)
#pragma unroll
      for (int r = 0; r < 4; ++r) {
        int gm = m0 + wr + i * 16 + fq * 4 + r;
        out[(size_t)gm * 1024 + gn] = acc[i][j][r] + bias;
      }
  }
}

extern "C" void kernel_launch(void* const* d_in, const int* in_sizes, int n_in,
                              void* d_out, int out_size, void* d_ws, size_t ws_size,
                              hipStream_t stream) {
  const float* x = (const float*)d_in[0];
  const float* Wq = (const float*)d_in[1];
  const float* bq = (const float*)d_in[2];
  const float* Wk = (const float*)d_in[3];
  const float* bk = (const float*)d_in[4];
  const float* Wv = (const float*)d_in[5];
  const float* bv = (const float*)d_in[6];
  const float* Wo = (const float*)d_in[7];
  const float* bo = (const float*)d_in[8];
  float* out = (float*)d_out;

  unsigned short* ws = (unsigned short*)d_ws;
  const size_t MI = (size_t)1024 * 1024;
  unsigned short* xb = ws;
  unsigned short* wt = ws + 4 * MI;
  unsigned short* qb = wt + 4 * MI;
  unsigned short* kb = qb + 4 * MI;
  unsigned short* vtb = kb + 4 * MI;
  unsigned short* attn = xb;  // reuse xb after QKV gemm

  prep_kernel<<<5120, 256, 0, stream>>>(x, Wq, Wk, Wv, Wo, xb, wt);
  gemm_qkv<<<dim3(32, 24), 256, 0, stream>>>(xb, wt, bq, bk, bv, qb, kb, vtb);
  attn_kernel<<<dim3(16, 32), 256, 0, stream>>>(qb, kb, vtb, attn);
  gemm_out<<<dim3(32, 8), 256, 0, stream>>>(attn, wt + 3 * MI, bo, out);
}

// Round 5
// 209.290 us; speedup vs baseline: 1.0265x; 1.0265x over previous
//
#include <hip/hip_runtime.h>
#include <hip/hip_bf16.h>
#include <stdint.h>

// Problem constants: B=2, S=2048, D=1024, H=16, DH=64, M = B*S = 4096.

typedef __attribute__((ext_vector_type(8))) short bf16x8;
typedef __attribute__((ext_vector_type(4))) float f32x4;

__device__ __forceinline__ void gld16(const void* g, void* l) {
  __builtin_amdgcn_global_load_lds((const __attribute__((address_space(1))) void*)g,
                                   (__attribute__((address_space(3))) void*)l, 16, 0, 0);
}

__device__ __forceinline__ unsigned short f2b(float f) {
  __hip_bfloat16 h = __float2bfloat16(f);
  return *reinterpret_cast<unsigned short*>(&h);
}

// ---------------- prep: x fp32->bf16 (blocks 0..4095) + W transpose (4096..5119) ----------------
__global__ __launch_bounds__(256) void prep_kernel(const float* __restrict__ x,
                                                   const float* __restrict__ Wq,
                                                   const float* __restrict__ Wk,
                                                   const float* __restrict__ Wv,
                                                   const float* __restrict__ Wo,
                                                   unsigned short* __restrict__ xb,
                                                   unsigned short* __restrict__ wt) {
  __shared__ unsigned short Ls[64 * 72];
  int bid = blockIdx.x;
  int t = threadIdx.x;
  if (bid < 4096) {
    int i = (bid * 256 + t) * 4;
    float4 v = *(const float4*)(x + i);
    ushort4 o = make_ushort4(f2b(v.x), f2b(v.y), f2b(v.z), f2b(v.w));
    *(ushort4*)(xb + i) = o;
    return;
  }
  int tid = bid - 4096;
  int z = tid >> 8, rem = tid & 255;
  int bx = rem & 15, by = rem >> 4;
  const float* src = (z == 0) ? Wq : (z == 1) ? Wk : (z == 2) ? Wv : Wo;
  unsigned short* dst = wt + (size_t)z * 1024 * 1024;
  int k0 = bx * 64, n0 = by * 64;
  int c4 = t & 15;
#pragma unroll
  for (int it = 0; it < 4; ++it) {
    int row = it * 16 + (t >> 4);
    float4 v = *(const float4*)(src + (k0 + row) * 1024 + n0 + c4 * 4);
    Ls[(c4 * 4 + 0) * 72 + row] = f2b(v.x);
    Ls[(c4 * 4 + 1) * 72 + row] = f2b(v.y);
    Ls[(c4 * 4 + 2) * 72 + row] = f2b(v.z);
    Ls[(c4 * 4 + 3) * 72 + row] = f2b(v.w);
  }
  __syncthreads();
  int nr = t >> 2, kc = (t & 3) * 16;
  *(uint4*)(dst + (size_t)(n0 + nr) * 1024 + k0 + kc) = *(uint4*)&Ls[nr * 72 + kc];
  *(uint4*)(dst + (size_t)(n0 + nr) * 1024 + k0 + kc + 8) = *(uint4*)&Ls[nr * 72 + kc + 8];
}

// ---------------- fused QKV GEMM (round-1 structure, passing) ----------------
// Q is pre-scaled by 0.125*log2(e) so attention can use raw exp2.
__global__ __launch_bounds__(256) void gemm_qkv(const unsigned short* __restrict__ Ab,
                                                const unsigned short* __restrict__ Bt,
                                                const float* __restrict__ bq,
                                                const float* __restrict__ bk,
                                                const float* __restrict__ bv,
                                                unsigned short* __restrict__ qb,
                                                unsigned short* __restrict__ kb,
                                                unsigned short* __restrict__ vtb) {
  __shared__ unsigned short As[128 * 32];
  __shared__ unsigned short Bs[128 * 32];
  __shared__ unsigned short Es[128 * 72];  // also viewed as [64][136] for V (9216 >= 8704)
  const int t = threadIdx.x;
  const int lane = t & 63, wave = t >> 6;
  const int m0 = blockIdx.x * 128, n0 = blockIdx.y * 128;
  const int wr = (wave >> 1) * 64, wc = (wave & 1) * 64;
  const int fr = lane & 15, fq = lane >> 4;
  f32x4 acc[4][4] = {};
  for (int kt = 0; kt < 32; ++kt) {
    const unsigned short* Ag = Ab + (size_t)m0 * 1024 + kt * 32;
    const unsigned short* Bg = Bt + (size_t)n0 * 1024 + kt * 32;
#pragma unroll
    for (int rep = 0; rep < 2; ++rep) {
      int c = t + rep * 256;
      int row = c >> 2, col = (c & 3) * 8;
      gld16(Ag + (size_t)row * 1024 + col, (void*)(As + c * 8));
      gld16(Bg + (size_t)row * 1024 + col, (void*)(Bs + c * 8));
    }
    __syncthreads();
    bf16x8 a[4], b[4];
#pragma unroll
    for (int i = 0; i < 4; ++i) a[i] = *(const bf16x8*)&As[(wr + i * 16 + fr) * 32 + fq * 8];
#pragma unroll
    for (int j = 0; j < 4; ++j) b[j] = *(const bf16x8*)&Bs[(wc + j * 16 + fr) * 32 + fq * 8];
#pragma unroll
    for (int i = 0; i < 4; ++i)
#pragma unroll
      for (int j = 0; j < 4; ++j)
        acc[i][j] = __builtin_amdgcn_mfma_f32_16x16x32_bf16(a[i], b[j], acc[i][j], 0, 0, 0);
    __syncthreads();
  }
  const int which = n0 >> 10;  // 0=q, 1=k, 2=v (uniform per block)
  const int bidx = m0 >> 11, s0 = m0 & 2047;
  if (which == 2) {
    // V: Es as [dh_l][136] (s-contig rows), b64 LDS writes, 256-B coalesced global rows.
#pragma unroll
    for (int nh = 0; nh < 2; ++nh) {
      if ((wc >> 6) == nh) {
#pragma unroll
        for (int j = 0; j < 4; ++j) {
          int col = j * 16 + fr;  // dh_l 0..63
          float bias = bv[(n0 + nh * 64 + col) & 1023];
#pragma unroll
          for (int i = 0; i < 4; ++i) {
            int sl = wr + i * 16 + fq * 4;
            ushort4 pk;
            pk.x = f2b(acc[i][j][0] + bias);
            pk.y = f2b(acc[i][j][1] + bias);
            pk.z = f2b(acc[i][j][2] + bias);
            pk.w = f2b(acc[i][j][3] + bias);
            *(uint2*)&Es[col * 136 + sl] = *(uint2*)&pk;
          }
        }
      }
      __syncthreads();
      int h = ((n0 + nh * 64) & 1023) >> 6;
#pragma unroll
      for (int it = 0; it < 4; ++it) {
        int dh = it * 16 + (t >> 4);
        int ck = (t & 15) * 8;
        uint4 vv = *(uint4*)&Es[dh * 136 + ck];
        *(uint4*)&vtb[(size_t)((bidx * 16 + h) * 64 + dh) * 2048 + s0 + ck] = vv;
      }
      __syncthreads();
    }
  } else {
    unsigned short* dst = (which == 0) ? qb : kb;
    const float* bias_p = (which == 0) ? bq : bk;
    float scale = (which == 0) ? 0.1803368801111204f : 1.0f;
#pragma unroll
    for (int nh = 0; nh < 2; ++nh) {
      if ((wc >> 6) == nh) {
#pragma unroll
        for (int j = 0; j < 4; ++j) {
          int col = j * 16 + fr;
          float bias = bias_p[(n0 + nh * 64 + col) & 1023];
#pragma unroll
          for (int i = 0; i < 4; ++i)
#pragma unroll
            for (int r = 0; r < 4; ++r) {
              int sl = wr + i * 16 + fq * 4 + r;
              Es[sl * 72 + col] = f2b((acc[i][j][r] + bias) * scale);
            }
        }
      }
      __syncthreads();
      int h = ((n0 + nh * 64) & 1023) >> 6;
#pragma unroll
      for (int it = 0; it < 4; ++it) {
        int sl = it * 32 + (t >> 3);
        int ck = (t & 7) * 8;
        uint4 vv = *(uint4*)&Es[sl * 72 + ck];
        *(uint4*)&dst[(size_t)((bidx * 16 + h) * 2048 + s0 + sl) * 64 + ck] = vv;
      }
      __syncthreads();
    }
  }
}

// ---------------- flash attention ----------------
// Occupancy doubling via SMALLER BLOCKS (not bigger): 4 waves x 16 q-rows,
// 64-row q-tile, grid 1024 blocks -> 4 blocks/CU (LDS 40KB) = 16 waves/CU,
// vs 8 waves/CU before. Same 256-thread shape / staging / launch_bounds as
// the round-1 passing kernel (the 512-thread variant failed the container
// twice; avoided). Per-wave work halves; 4 independent barrier groups per CU.
__global__ __launch_bounds__(256, 2) void attn_kernel(const unsigned short* __restrict__ qb,
                                                      const unsigned short* __restrict__ kb,
                                                      const unsigned short* __restrict__ vtb,
                                                      unsigned short* __restrict__ attn) {
  __shared__ unsigned short Ks[2 * 4096];
  __shared__ unsigned short Vs[2 * 4096];
  __shared__ unsigned short Ps[4 * 1024];
  const int t = threadIdx.x, lane = t & 63, w = t >> 6;
  const int fr = lane & 15, fq = lane >> 4;
  // XCD-aware bijective remap over 1024 blocks: xcd = rid&7 owns 4 heads
  // (bh = xcd + 8*(rid>>8)); q-tile = (rid>>3)&31. 4 heads x 512KB KV = 2MB/L2.
  const int rid = blockIdx.y * 32 + blockIdx.x;
  const int bh = (rid & 7) + ((rid >> 8) << 3);
  const int q0 = ((rid >> 3) & 31) * 64;
  // Read-side chunk XOR matching the pre-swizzled staging below.
  const int ksel = (fq ^ ((fr >> 1) & 3)) * 8;
  const unsigned short* qg = qb + (size_t)bh * 2048 * 64;
  const unsigned short* kg0 = kb + (size_t)bh * 2048 * 64;
  const unsigned short* vg0 = vtb + (size_t)bh * 64 * 2048;

  // Each wave owns 16 q-rows: q = q0 + w*16 + fr.
  bf16x8 qf[2];
#pragma unroll
  for (int kk = 0; kk < 2; ++kk)
    qf[kk] = *(const bf16x8*)(qg + (size_t)(q0 + w * 16 + fr) * 64 + kk * 32 + fq * 8);

  bf16x8 ones;
#pragma unroll
  for (int i = 0; i < 8; ++i) ones[i] = (short)0x3F80;

  f32x4 oacc[4] = {};
  f32x4 lacc = {};
  unsigned short* Pw = Ps + w * 1024;  // [16 rows][64 shorts], XOR-swizzled chunks

  {  // prologue: stage kt=0 (verbatim round-1 staging)
#pragma unroll
    for (int rep = 0; rep < 2; ++rep) {
      int c = t + rep * 256;
      int kk = c >> 8, row = (c >> 2) & 63, cc = c & 3;
      int cs = cc ^ ((row >> 1) & 3);  // pre-swizzle global source chunk
      gld16(kg0 + row * 64 + kk * 32 + cs * 8, (void*)(Ks + c * 8));
      gld16(vg0 + (size_t)row * 2048 + kk * 32 + cs * 8, (void*)(Vs + c * 8));
    }
  }

  for (int kt = 0; kt < 32; ++kt) {
    int buf = kt & 1;
    __syncthreads();
    if (kt + 1 < 32) {
      const unsigned short* kg = kg0 + (size_t)(kt + 1) * 4096;
      const unsigned short* vg = vg0 + (kt + 1) * 64;
      int lb = (buf ^ 1) * 4096;
#pragma unroll
      for (int rep = 0; rep < 2; ++rep) {
        int c = t + rep * 256;
        int kk = c >> 8, row = (c >> 2) & 63, cc = c & 3;
        int cs = cc ^ ((row >> 1) & 3);
        gld16(kg + row * 64 + kk * 32 + cs * 8, (void*)(Ks + lb + c * 8));
        gld16(vg + (size_t)row * 2048 + kk * 32 + cs * 8, (void*)(Vs + lb + c * 8));
      }
    }
    const unsigned short* Kb = Ks + buf * 4096;
    const unsigned short* Vb = Vs + buf * 4096;
    // QK^T: sacc[m][r] = S[k = m*16 + fq*4 + r][q = fr]
    f32x4 sacc[4] = {};
#pragma unroll
    for (int kk = 0; kk < 2; ++kk) {
      bf16x8 kf[4];
#pragma unroll
      for (int m = 0; m < 4; ++m) kf[m] = *(const bf16x8*)&Kb[kk * 2048 + (m * 16 + fr) * 32 + ksel];
      __builtin_amdgcn_s_setprio(1);
#pragma unroll
      for (int m = 0; m < 4; ++m)
        sacc[m] = __builtin_amdgcn_mfma_f32_16x16x32_bf16(kf[m], qf[kk], sacc[m], 0, 0, 0);
      __builtin_amdgcn_s_setprio(0);
    }
    // softmax numerator -> P tile in LDS (XOR-swizzled chunks, conflict-free)
#pragma unroll
    for (int m = 0; m < 4; ++m) {
      int G = (m * 2 + (fq >> 1)) ^ (fr & 7);
      ushort4 pk;
      pk.x = f2b(__builtin_amdgcn_exp2f(sacc[m][0]));
      pk.y = f2b(__builtin_amdgcn_exp2f(sacc[m][1]));
      pk.z = f2b(__builtin_amdgcn_exp2f(sacc[m][2]));
      pk.w = f2b(__builtin_amdgcn_exp2f(sacc[m][3]));
      *(uint2*)&Pw[fr * 64 + G * 8 + (fq & 1) * 4] = *(uint2*)&pk;
    }
    // PV: oacc[n] += P[q][s] * V^T[dh][s]
#pragma unroll
    for (int kk = 0; kk < 2; ++kk) {
      int G = (kk * 4 + fq) ^ (fr & 7);
      bf16x8 pf = *(const bf16x8*)&Pw[fr * 64 + G * 8];
      __builtin_amdgcn_s_setprio(1);
#pragma unroll
      for (int n = 0; n < 4; ++n) {
        bf16x8 vf = *(const bf16x8*)&Vb[kk * 2048 + (n * 16 + fr) * 32 + ksel];
        oacc[n] = __builtin_amdgcn_mfma_f32_16x16x32_bf16(pf, vf, oacc[n], 0, 0, 0);
      }
      lacc = __builtin_amdgcn_mfma_f32_16x16x32_bf16(pf, ones, lacc, 0, 0, 0);
      __builtin_amdgcn_s_setprio(0);
    }
  }
  int bidx = bh >> 4, h = bh & 15;
#pragma unroll
  for (int r = 0; r < 4; ++r) {
    float inv = 1.f / lacc[r];
    int s = q0 + w * 16 + fq * 4 + r;
    size_t base = (size_t)(bidx * 2048 + s) * 1024 + h * 64;
#pragma unroll
    for (int n = 0; n < 4; ++n) attn[base + n * 16 + fr] = f2b(oacc[n][r] * inv);
  }
}

// ---------------- output projection (round-1 structure, passing) ----------------
__global__ __launch_bounds__(256) void gemm_out(const unsigned short* __restrict__ Ab,
                                                const unsigned short* __restrict__ Bt,
                                                const float* __restrict__ bo,
                                                float* __restrict__ out) {
  __shared__ unsigned short As[128 * 32];
  __shared__ unsigned short Bs[128 * 32];
  const int t = threadIdx.x;
  const int lane = t & 63, wave = t >> 6;
  const int m0 = blockIdx.x * 128, n0 = blockIdx.y * 128;
  const int wr = (wave >> 1) * 64, wc = (wave & 1) * 64;
  const int fr = lane & 15, fq = lane >> 4;
  f32x4 acc[4][4] = {};
  for (int kt = 0; kt < 32; ++kt) {
    const unsigned short* Ag = Ab + (size_t)m0 * 1024 + kt * 32;
    const unsigned short* Bg = Bt + (size_t)n0 * 1024 + kt * 32;
#pragma unroll
    for (int rep = 0; rep < 2; ++rep) {
      int c = t + rep * 256;
      int row = c >> 2, col = (c & 3) * 8;
      gld16(Ag + (size_t)row * 1024 + col, (void*)(As + c * 8));
      gld16(Bg + (size_t)row * 1024 + col, (void*)(Bs + c * 8));
    }
    __syncthreads();
    bf16x8 a[4], b[4];
#pragma unroll
    for (int i = 0; i < 4; ++i) a[i] = *(const bf16x8*)&As[(wr + i * 16 + fr) * 32 + fq * 8];
#pragma unroll
    for (int j = 0; j < 4; ++j) b[j] = *(const bf16x8*)&Bs[(wc + j * 16 + fr) * 32 + fq * 8];
#pragma unroll
    for (int i = 0; i < 4; ++i)
#pragma unroll
      for (int j = 0; j < 4; ++j)
        acc[i][j] = __builtin_amdgcn_mfma_f32_16x16x32_bf16(a[i], b[j], acc[i][j], 0, 0, 0);
    __syncthreads();
  }
#pragma unroll
  for (int j = 0; j < 4; ++j) {
    int gn = n0 + wc + j * 16 + fr;
    float bias = bo[gn];
#pragma unroll
    for (int i = 0; i < 4; ++i)
#pragma unroll
      for (int r = 0; r < 4; ++r) {
        int gm = m0 + wr + i * 16 + fq * 4 + r;
        out[(size_t)gm * 1024 + gn] = acc[i][j][r] + bias;
      }
  }
}

extern "C" void kernel_launch(void* const* d_in, const int* in_sizes, int n_in,
                              void* d_out, int out_size, void* d_ws, size_t ws_size,
                              hipStream_t stream) {
  const float* x = (const float*)d_in[0];
  const float* Wq = (const float*)d_in[1];
  const float* bq = (const float*)d_in[2];
  const float* Wk = (const float*)d_in[3];
  const float* bk = (const float*)d_in[4];
  const float* Wv = (const float*)d_in[5];
  const float* bv = (const float*)d_in[6];
  const float* Wo = (const float*)d_in[7];
  const float* bo = (const float*)d_in[8];
  float* out = (float*)d_out;

  unsigned short* ws = (unsigned short*)d_ws;
  const size_t MI = (size_t)1024 * 1024;
  unsigned short* xb = ws;
  unsigned short* wt = ws + 4 * MI;
  unsigned short* qb = wt + 4 * MI;
  unsigned short* kb = qb + 4 * MI;
  unsigned short* vtb = kb + 4 * MI;
  unsigned short* attn = xb;  // reuse xb after QKV gemm

  prep_kernel<<<5120, 256, 0, stream>>>(x, Wq, Wk, Wv, Wo, xb, wt);
  gemm_qkv<<<dim3(32, 24), 256, 0, stream>>>(xb, wt, bq, bk, bv, qb, kb, vtb);
  attn_kernel<<<dim3(32, 32), 256, 0, stream>>>(qb, kb, vtb, attn);
  gemm_out<<<dim3(32, 8), 256, 0, stream>>>(attn, wt + 3 * MI, bo, out);
}

// Round 6
// 208.922 us; speedup vs baseline: 1.0283x; 1.0018x over previous
//
#include <hip/hip_runtime.h>
#include <hip/hip_bf16.h>
#include <stdint.h>

// Problem constants: B=2, S=2048, D=1024, H=16, DH=64, M = B*S = 4096.

typedef __attribute__((ext_vector_type(8))) short bf16x8;
typedef __attribute__((ext_vector_type(4))) float f32x4;
typedef __attribute__((ext_vector_type(16))) float f32x16;

__device__ __forceinline__ void gld16(const void* g, void* l) {
  __builtin_amdgcn_global_load_lds((const __attribute__((address_space(1))) void*)g,
                                   (__attribute__((address_space(3))) void*)l, 16, 0, 0);
}

__device__ __forceinline__ unsigned short f2b(float f) {
  __hip_bfloat16 h = __float2bfloat16(f);
  return *reinterpret_cast<unsigned short*>(&h);
}

// ---------------- prep: x fp32->bf16 (blocks 0..4095) + W transpose (4096..5119) ----------------
__global__ __launch_bounds__(256) void prep_kernel(const float* __restrict__ x,
                                                   const float* __restrict__ Wq,
                                                   const float* __restrict__ Wk,
                                                   const float* __restrict__ Wv,
                                                   const float* __restrict__ Wo,
                                                   unsigned short* __restrict__ xb,
                                                   unsigned short* __restrict__ wt) {
  __shared__ unsigned short Ls[64 * 72];
  int bid = blockIdx.x;
  int t = threadIdx.x;
  if (bid < 4096) {
    int i = (bid * 256 + t) * 4;
    float4 v = *(const float4*)(x + i);
    ushort4 o = make_ushort4(f2b(v.x), f2b(v.y), f2b(v.z), f2b(v.w));
    *(ushort4*)(xb + i) = o;
    return;
  }
  int tid = bid - 4096;
  int z = tid >> 8, rem = tid & 255;
  int bx = rem & 15, by = rem >> 4;
  const float* src = (z == 0) ? Wq : (z == 1) ? Wk : (z == 2) ? Wv : Wo;
  unsigned short* dst = wt + (size_t)z * 1024 * 1024;
  int k0 = bx * 64, n0 = by * 64;
  int c4 = t & 15;
#pragma unroll
  for (int it = 0; it < 4; ++it) {
    int row = it * 16 + (t >> 4);
    float4 v = *(const float4*)(src + (k0 + row) * 1024 + n0 + c4 * 4);
    Ls[(c4 * 4 + 0) * 72 + row] = f2b(v.x);
    Ls[(c4 * 4 + 1) * 72 + row] = f2b(v.y);
    Ls[(c4 * 4 + 2) * 72 + row] = f2b(v.z);
    Ls[(c4 * 4 + 3) * 72 + row] = f2b(v.w);
  }
  __syncthreads();
  int nr = t >> 2, kc = (t & 3) * 16;
  *(uint4*)(dst + (size_t)(n0 + nr) * 1024 + k0 + kc) = *(uint4*)&Ls[nr * 72 + kc];
  *(uint4*)(dst + (size_t)(n0 + nr) * 1024 + k0 + kc + 8) = *(uint4*)&Ls[nr * 72 + kc + 8];
}

// ---------------- fused QKV GEMM (round-1 structure, passing) ----------------
// Q is pre-scaled by 0.125*log2(e) so attention can use raw exp2.
__global__ __launch_bounds__(256) void gemm_qkv(const unsigned short* __restrict__ Ab,
                                                const unsigned short* __restrict__ Bt,
                                                const float* __restrict__ bq,
                                                const float* __restrict__ bk,
                                                const float* __restrict__ bv,
                                                unsigned short* __restrict__ qb,
                                                unsigned short* __restrict__ kb,
                                                unsigned short* __restrict__ vtb) {
  __shared__ unsigned short As[128 * 32];
  __shared__ unsigned short Bs[128 * 32];
  __shared__ unsigned short Es[128 * 72];  // also viewed as [64][136] for V (9216 >= 8704)
  const int t = threadIdx.x;
  const int lane = t & 63, wave = t >> 6;
  const int m0 = blockIdx.x * 128, n0 = blockIdx.y * 128;
  const int wr = (wave >> 1) * 64, wc = (wave & 1) * 64;
  const int fr = lane & 15, fq = lane >> 4;
  f32x4 acc[4][4] = {};
  for (int kt = 0; kt < 32; ++kt) {
    const unsigned short* Ag = Ab + (size_t)m0 * 1024 + kt * 32;
    const unsigned short* Bg = Bt + (size_t)n0 * 1024 + kt * 32;
#pragma unroll
    for (int rep = 0; rep < 2; ++rep) {
      int c = t + rep * 256;
      int row = c >> 2, col = (c & 3) * 8;
      gld16(Ag + (size_t)row * 1024 + col, (void*)(As + c * 8));
      gld16(Bg + (size_t)row * 1024 + col, (void*)(Bs + c * 8));
    }
    __syncthreads();
    bf16x8 a[4], b[4];
#pragma unroll
    for (int i = 0; i < 4; ++i) a[i] = *(const bf16x8*)&As[(wr + i * 16 + fr) * 32 + fq * 8];
#pragma unroll
    for (int j = 0; j < 4; ++j) b[j] = *(const bf16x8*)&Bs[(wc + j * 16 + fr) * 32 + fq * 8];
#pragma unroll
    for (int i = 0; i < 4; ++i)
#pragma unroll
      for (int j = 0; j < 4; ++j)
        acc[i][j] = __builtin_amdgcn_mfma_f32_16x16x32_bf16(a[i], b[j], acc[i][j], 0, 0, 0);
    __syncthreads();
  }
  const int which = n0 >> 10;  // 0=q, 1=k, 2=v (uniform per block)
  const int bidx = m0 >> 11, s0 = m0 & 2047;
  if (which == 2) {
    // V: Es as [dh_l][136] (s-contig rows), b64 LDS writes, 256-B coalesced global rows.
#pragma unroll
    for (int nh = 0; nh < 2; ++nh) {
      if ((wc >> 6) == nh) {
#pragma unroll
        for (int j = 0; j < 4; ++j) {
          int col = j * 16 + fr;  // dh_l 0..63
          float bias = bv[(n0 + nh * 64 + col) & 1023];
#pragma unroll
          for (int i = 0; i < 4; ++i) {
            int sl = wr + i * 16 + fq * 4;
            ushort4 pk;
            pk.x = f2b(acc[i][j][0] + bias);
            pk.y = f2b(acc[i][j][1] + bias);
            pk.z = f2b(acc[i][j][2] + bias);
            pk.w = f2b(acc[i][j][3] + bias);
            *(uint2*)&Es[col * 136 + sl] = *(uint2*)&pk;
          }
        }
      }
      __syncthreads();
      int h = ((n0 + nh * 64) & 1023) >> 6;
#pragma unroll
      for (int it = 0; it < 4; ++it) {
        int dh = it * 16 + (t >> 4);
        int ck = (t & 15) * 8;
        uint4 vv = *(uint4*)&Es[dh * 136 + ck];
        *(uint4*)&vtb[(size_t)((bidx * 16 + h) * 64 + dh) * 2048 + s0 + ck] = vv;
      }
      __syncthreads();
    }
  } else {
    unsigned short* dst = (which == 0) ? qb : kb;
    const float* bias_p = (which == 0) ? bq : bk;
    float scale = (which == 0) ? 0.1803368801111204f : 1.0f;
#pragma unroll
    for (int nh = 0; nh < 2; ++nh) {
      if ((wc >> 6) == nh) {
#pragma unroll
        for (int j = 0; j < 4; ++j) {
          int col = j * 16 + fr;
          float bias = bias_p[(n0 + nh * 64 + col) & 1023];
#pragma unroll
          for (int i = 0; i < 4; ++i)
#pragma unroll
            for (int r = 0; r < 4; ++r) {
              int sl = wr + i * 16 + fq * 4 + r;
              Es[sl * 72 + col] = f2b((acc[i][j][r] + bias) * scale);
            }
        }
      }
      __syncthreads();
      int h = ((n0 + nh * 64) & 1023) >> 6;
#pragma unroll
      for (int it = 0; it < 4; ++it) {
        int sl = it * 32 + (t >> 3);
        int ck = (t & 7) * 8;
        uint4 vv = *(uint4*)&Es[sl * 72 + ck];
        *(uint4*)&dst[(size_t)((bidx * 16 + h) * 2048 + s0 + sl) * 64 + ck] = vv;
      }
      __syncthreads();
    }
  }
}

// ---------------- flash attention ----------------
// Round-7: attn measured LDS-BW-bound (~90 B/cyc/CU vs 128 peak; occupancy
// doubling was a no-op). Switch QK^T and PV to mfma_32x32x16: halves LDS
// bytes per MAC (16B frag per 1024 outputs*K16 vs per 256*K32). 4 waves x
// 32 q-rows = 128-q blocks, grid 512. K/V staging + chunk-XOR layout
// UNCHANGED (verified bank-balanced for the 32x32 frag read pattern).
// Swapped-QK C/D layout (col=lane&31=q) makes the softmax denominator a
// lane-local VALU sum + one shfl_xor(32) -- lacc MFMAs deleted.
// P tile: per-wave [32 q][64 k] bf16 with byte-XOR ((q&7)<<4) -> both the
// 8B writes and 16B A-frag reads are bank-balanced.
__global__ __launch_bounds__(256, 2) void attn_kernel(const unsigned short* __restrict__ qb,
                                                      const unsigned short* __restrict__ kb,
                                                      const unsigned short* __restrict__ vtb,
                                                      unsigned short* __restrict__ attn) {
  __shared__ unsigned short Ks[2 * 4096];
  __shared__ unsigned short Vs[2 * 4096];
  __shared__ unsigned short Ps[4 * 2048];  // 4 waves x [32 q][64 k] bf16 (4KB each)
  __shared__ float Linv[4][32];
  const int t = threadIdx.x, lane = t & 63, w = t >> 6;
  const int qh = lane & 31, hi = lane >> 5;
  const int rid = blockIdx.y * 16 + blockIdx.x;
  const int bh = (rid & 7) + ((rid >> 7) << 3);
  const int q0 = ((rid >> 3) & 15) * 128;
  const unsigned short* qg = qb + (size_t)bh * 2048 * 64;
  const unsigned short* kg0 = kb + (size_t)bh * 2048 * 64;
  const unsigned short* vg0 = vtb + (size_t)bh * 64 * 2048;

  // Each wave owns 32 q-rows: q = q0 + w*32 + qh. B-frag: col=qh, k=hi*8+e.
  bf16x8 qf[4];
#pragma unroll
  for (int st = 0; st < 4; ++st)
    qf[st] = *(const bf16x8*)(qg + (size_t)(q0 + w * 32 + qh) * 64 + st * 16 + hi * 8);

  f32x16 oacc[2] = {};
  float lsum = 0.f;
  char* PwB = (char*)Ps + w * 4096;
  const int swz = (qh & 7) << 4;

  {  // prologue: stage kt=0 (verbatim round-1 staging)
#pragma unroll
    for (int rep = 0; rep < 2; ++rep) {
      int c = t + rep * 256;
      int kk = c >> 8, row = (c >> 2) & 63, cc = c & 3;
      int cs = cc ^ ((row >> 1) & 3);  // pre-swizzle global source chunk
      gld16(kg0 + row * 64 + kk * 32 + cs * 8, (void*)(Ks + c * 8));
      gld16(vg0 + (size_t)row * 2048 + kk * 32 + cs * 8, (void*)(Vs + c * 8));
    }
  }

  for (int kt = 0; kt < 32; ++kt) {
    int buf = kt & 1;
    __syncthreads();
    if (kt + 1 < 32) {
      const unsigned short* kg = kg0 + (size_t)(kt + 1) * 4096;
      const unsigned short* vg = vg0 + (kt + 1) * 64;
      int lb = (buf ^ 1) * 4096;
#pragma unroll
      for (int rep = 0; rep < 2; ++rep) {
        int c = t + rep * 256;
        int kk = c >> 8, row = (c >> 2) & 63, cc = c & 3;
        int cs = cc ^ ((row >> 1) & 3);
        gld16(kg + row * 64 + kk * 32 + cs * 8, (void*)(Ks + lb + c * 8));
        gld16(vg + (size_t)row * 2048 + kk * 32 + cs * 8, (void*)(Vs + lb + c * 8));
      }
    }
    const unsigned short* Kb = Ks + buf * 4096;
    const unsigned short* Vb = Vs + buf * 4096;
    // QK^T: sacc[m] = S[k = m*32 + (r&3)+8*(r>>2)+4*hi][q = qh]
    f32x16 sacc[2] = {};
    __builtin_amdgcn_s_setprio(1);
#pragma unroll
    for (int st = 0; st < 4; ++st) {
#pragma unroll
      for (int m = 0; m < 2; ++m) {
        int s = m * 32 + qh;
        int cs = ((st & 1) * 2 + hi) ^ ((s >> 1) & 3);
        bf16x8 kf = *(const bf16x8*)&Kb[(st >> 1) * 2048 + s * 32 + cs * 8];
        sacc[m] = __builtin_amdgcn_mfma_f32_32x32x16_bf16(kf, qf[st], sacc[m], 0, 0, 0);
      }
    }
    __builtin_amdgcn_s_setprio(0);
    // softmax numerator -> per-wave P tile (lane-local row sum accumulates lsum)
#pragma unroll
    for (int m = 0; m < 2; ++m)
#pragma unroll
      for (int g = 0; g < 4; ++g) {
        float e0 = __builtin_amdgcn_exp2f(sacc[m][g * 4 + 0]);
        float e1 = __builtin_amdgcn_exp2f(sacc[m][g * 4 + 1]);
        float e2 = __builtin_amdgcn_exp2f(sacc[m][g * 4 + 2]);
        float e3 = __builtin_amdgcn_exp2f(sacc[m][g * 4 + 3]);
        lsum += (e0 + e1) + (e2 + e3);
        ushort4 pk = make_ushort4(f2b(e0), f2b(e1), f2b(e2), f2b(e3));
        int kbyte = m * 64 + g * 16 + hi * 8;  // k = m*32+g*8+hi*4 (+0..3)
        *(uint2*)(PwB + qh * 128 + (kbyte ^ swz)) = *(uint2*)&pk;
      }
    // PV: oacc[n] += P[q][s] * V^T[dh][s]; A-frag row=qh, k=st*16+hi*8+e
    __builtin_amdgcn_s_setprio(1);
#pragma unroll
    for (int st = 0; st < 4; ++st) {
      int kbyte = st * 32 + hi * 16;
      bf16x8 pf = *(const bf16x8*)(PwB + qh * 128 + (kbyte ^ swz));
#pragma unroll
      for (int n = 0; n < 2; ++n) {
        int dh = n * 32 + qh;
        int cs = ((st & 1) * 2 + hi) ^ ((dh >> 1) & 3);
        bf16x8 vf = *(const bf16x8*)&Vb[(st >> 1) * 2048 + dh * 32 + cs * 8];
        oacc[n] = __builtin_amdgcn_mfma_f32_32x32x16_bf16(pf, vf, oacc[n], 0, 0, 0);
      }
    }
    __builtin_amdgcn_s_setprio(0);
  }
  // epilogue: combine half-wave partial sums (lane l and l^32 share q=qh)
  lsum += __shfl_xor(lsum, 32);
  Linv[w][qh] = 1.f / lsum;  // both halves write the same value
  int bidx = bh >> 4, h = bh & 15;
#pragma unroll
  for (int r = 0; r < 16; ++r) {
    int qloc = (r & 3) + 8 * (r >> 2) + 4 * hi;
    float iv = Linv[w][qloc];
    int s = q0 + w * 32 + qloc;
    size_t base = (size_t)(bidx * 2048 + s) * 1024 + h * 64;
#pragma unroll
    for (int n = 0; n < 2; ++n) attn[base + n * 32 + qh] = f2b(oacc[n][r] * iv);
  }
}

// ---------------- output projection (round-1 structure, passing) ----------------
__global__ __launch_bounds__(256) void gemm_out(const unsigned short* __restrict__ Ab,
                                                const unsigned short* __restrict__ Bt,
                                                const float* __restrict__ bo,
                                                float* __restrict__ out) {
  __shared__ unsigned short As[128 * 32];
  __shared__ unsigned short Bs[128 * 32];
  const int t = threadIdx.x;
  const int lane = t & 63, wave = t >> 6;
  const int m0 = blockIdx.x * 128, n0 = blockIdx.y * 128;
  const int wr = (wave >> 1) * 64, wc = (wave & 1) * 64;
  const int fr = lane & 15, fq = lane >> 4;
  f32x4 acc[4][4] = {};
  for (int kt = 0; kt < 32; ++kt) {
    const unsigned short* Ag = Ab + (size_t)m0 * 1024 + kt * 32;
    const unsigned short* Bg = Bt + (size_t)n0 * 1024 + kt * 32;
#pragma unroll
    for (int rep = 0; rep < 2; ++rep) {
      int c = t + rep * 256;
      int row = c >> 2, col = (c & 3) * 8;
      gld16(Ag + (size_t)row * 1024 + col, (void*)(As + c * 8));
      gld16(Bg + (size_t)row * 1024 + col, (void*)(Bs + c * 8));
    }
    __syncthreads();
    bf16x8 a[4], b[4];
#pragma unroll
    for (int i = 0; i < 4; ++i) a[i] = *(const bf16x8*)&As[(wr + i * 16 + fr) * 32 + fq * 8];
#pragma unroll
    for (int j = 0; j < 4; ++j) b[j] = *(const bf16x8*)&Bs[(wc + j * 16 + fr) * 32 + fq * 8];
#pragma unroll
    for (int i = 0; i < 4; ++i)
#pragma unroll
      for (int j = 0; j < 4; ++j)
        acc[i][j] = __builtin_amdgcn_mfma_f32_16x16x32_bf16(a[i], b[j], acc[i][j], 0, 0, 0);
    __syncthreads();
  }
#pragma unroll
  for (int j = 0; j < 4; ++j) {
    int gn = n0 + wc + j * 16 + fr;
    float bias = bo[gn];
#pragma unroll
    for (int i = 0; i < 4; ++i)
#pragma unroll
      for (int r = 0; r < 4; ++r) {
        int gm = m0 + wr + i * 16 + fq * 4 + r;
        out[(size_t)gm * 1024 + gn] = acc[i][j][r] + bias;
      }
  }
}

extern "C" void kernel_launch(void* const* d_in, const int* in_sizes, int n_in,
                              void* d_out, int out_size, void* d_ws, size_t ws_size,
                              hipStream_t stream) {
  const float* x = (const float*)d_in[0];
  const float* Wq = (const float*)d_in[1];
  const float* bq = (const float*)d_in[2];
  const float* Wk = (const float*)d_in[3];
  const float* bk = (const float*)d_in[4];
  const float* Wv = (const float*)d_in[5];
  const float* bv = (const float*)d_in[6];
  const float* Wo = (const float*)d_in[7];
  const float* bo = (const float*)d_in[8];
  float* out = (float*)d_out;

  unsigned short* ws = (unsigned short*)d_ws;
  const size_t MI = (size_t)1024 * 1024;
  unsigned short* xb = ws;
  unsigned short* wt = ws + 4 * MI;
  unsigned short* qb = wt + 4 * MI;
  unsigned short* kb = qb + 4 * MI;
  unsigned short* vtb = kb + 4 * MI;
  unsigned short* attn = xb;  // reuse xb after QKV gemm

  prep_kernel<<<5120, 256, 0, stream>>>(x, Wq, Wk, Wv, Wo, xb, wt);
  gemm_qkv<<<dim3(32, 24), 256, 0, stream>>>(xb, wt, bq, bk, bv, qb, kb, vtb);
  attn_kernel<<<dim3(16, 32), 256, 0, stream>>>(qb, kb, vtb, attn);
  gemm_out<<<dim3(32, 8), 256, 0, stream>>>(attn, wt + 3 * MI, bo, out);
}

// Round 7
// 196.803 us; speedup vs baseline: 1.0916x; 1.0616x over previous
//
#include <hip/hip_runtime.h>
#include <hip/hip_bf16.h>
#include <stdint.h>

// Problem constants: B=2, S=2048, D=1024, H=16, DH=64, M = B*S = 4096.

typedef __attribute__((ext_vector_type(8))) short bf16x8;
typedef __attribute__((ext_vector_type(4))) float f32x4;

__device__ __forceinline__ void gld16(const void* g, void* l) {
  __builtin_amdgcn_global_load_lds((const __attribute__((address_space(1))) void*)g,
                                   (__attribute__((address_space(3))) void*)l, 16, 0, 0);
}

__device__ __forceinline__ unsigned short f2b(float f) {
  __hip_bfloat16 h = __float2bfloat16(f);
  return *reinterpret_cast<unsigned short*>(&h);
}

// ---------------- prep: x fp32->bf16 (blocks 0..4095) + W transpose (4096..5119) ----------------
__global__ __launch_bounds__(256) void prep_kernel(const float* __restrict__ x,
                                                   const float* __restrict__ Wq,
                                                   const float* __restrict__ Wk,
                                                   const float* __restrict__ Wv,
                                                   const float* __restrict__ Wo,
                                                   unsigned short* __restrict__ xb,
                                                   unsigned short* __restrict__ wt) {
  __shared__ unsigned short Ls[64 * 72];
  int bid = blockIdx.x;
  int t = threadIdx.x;
  if (bid < 4096) {
    int i = (bid * 256 + t) * 4;
    float4 v = *(const float4*)(x + i);
    ushort4 o = make_ushort4(f2b(v.x), f2b(v.y), f2b(v.z), f2b(v.w));
    *(ushort4*)(xb + i) = o;
    return;
  }
  int tid = bid - 4096;
  int z = tid >> 8, rem = tid & 255;
  int bx = rem & 15, by = rem >> 4;
  const float* src = (z == 0) ? Wq : (z == 1) ? Wk : (z == 2) ? Wv : Wo;
  unsigned short* dst = wt + (size_t)z * 1024 * 1024;
  int k0 = bx * 64, n0 = by * 64;
  int c4 = t & 15;
#pragma unroll
  for (int it = 0; it < 4; ++it) {
    int row = it * 16 + (t >> 4);
    float4 v = *(const float4*)(src + (k0 + row) * 1024 + n0 + c4 * 4);
    Ls[(c4 * 4 + 0) * 72 + row] = f2b(v.x);
    Ls[(c4 * 4 + 1) * 72 + row] = f2b(v.y);
    Ls[(c4 * 4 + 2) * 72 + row] = f2b(v.z);
    Ls[(c4 * 4 + 3) * 72 + row] = f2b(v.w);
  }
  __syncthreads();
  int nr = t >> 2, kc = (t & 3) * 16;
  *(uint4*)(dst + (size_t)(n0 + nr) * 1024 + k0 + kc) = *(uint4*)&Ls[nr * 72 + kc];
  *(uint4*)(dst + (size_t)(n0 + nr) * 1024 + k0 + kc + 8) = *(uint4*)&Ls[nr * 72 + kc + 8];
}

// ---------------- fused QKV GEMM ----------------
// Round-7: BK=64 (16 K-steps, half the barrier+vmcnt(0) drains). Row stride
// is now 128B, so As/Bs use the XOR chunk swizzle (chunk ^= row&7) applied
// BOTH at stage (pre-swizzled global source, linear LDS dest) and at read --
// same involution pattern as the attn K/V tiles. LDS 50.4KB -> 3 blocks/CU
// (grid-limited at 3 anyway). Q is pre-scaled by 0.125*log2(e).
__global__ __launch_bounds__(256) void gemm_qkv(const unsigned short* __restrict__ Ab,
                                                const unsigned short* __restrict__ Bt,
                                                const float* __restrict__ bq,
                                                const float* __restrict__ bk,
                                                const float* __restrict__ bv,
                                                unsigned short* __restrict__ qb,
                                                unsigned short* __restrict__ kb,
                                                unsigned short* __restrict__ vtb) {
  __shared__ unsigned short As[128 * 64];
  __shared__ unsigned short Bs[128 * 64];
  __shared__ unsigned short Es[128 * 72];  // also viewed as [64][136] for V (9216 >= 8704)
  const int t = threadIdx.x;
  const int lane = t & 63, wave = t >> 6;
  const int m0 = blockIdx.x * 128, n0 = blockIdx.y * 128;
  const int wr = (wave >> 1) * 64, wc = (wave & 1) * 64;
  const int fr = lane & 15, fq = lane >> 4;
  f32x4 acc[4][4] = {};
  for (int kt = 0; kt < 16; ++kt) {
    const unsigned short* Ag = Ab + (size_t)m0 * 1024 + kt * 64;
    const unsigned short* Bg = Bt + (size_t)n0 * 1024 + kt * 64;
#pragma unroll
    for (int rep = 0; rep < 4; ++rep) {
      int c = t + rep * 256;
      int row = c >> 3, ch = (c & 7) ^ (row & 7);  // pre-swizzled source chunk
      gld16(Ag + (size_t)row * 1024 + ch * 8, (void*)(As + c * 8));
      gld16(Bg + (size_t)row * 1024 + ch * 8, (void*)(Bs + c * 8));
    }
    __syncthreads();
    bf16x8 a[4][2], b[4][2];
#pragma unroll
    for (int i = 0; i < 4; ++i) {
      int r = wr + i * 16 + fr;
#pragma unroll
      for (int kk = 0; kk < 2; ++kk)
        a[i][kk] = *(const bf16x8*)&As[r * 64 + ((kk * 4 + fq) ^ (r & 7)) * 8];
    }
#pragma unroll
    for (int j = 0; j < 4; ++j) {
      int r = wc + j * 16 + fr;
#pragma unroll
      for (int kk = 0; kk < 2; ++kk)
        b[j][kk] = *(const bf16x8*)&Bs[r * 64 + ((kk * 4 + fq) ^ (r & 7)) * 8];
    }
#pragma unroll
    for (int kk = 0; kk < 2; ++kk)
#pragma unroll
      for (int i = 0; i < 4; ++i)
#pragma unroll
        for (int j = 0; j < 4; ++j)
          acc[i][j] = __builtin_amdgcn_mfma_f32_16x16x32_bf16(a[i][kk], b[j][kk], acc[i][j], 0, 0, 0);
    __syncthreads();
  }
  const int which = n0 >> 10;  // 0=q, 1=k, 2=v (uniform per block)
  const int bidx = m0 >> 11, s0 = m0 & 2047;
  if (which == 2) {
    // V: Es as [dh_l][136] (s-contig rows), b64 LDS writes, 256-B coalesced global rows.
#pragma unroll
    for (int nh = 0; nh < 2; ++nh) {
      if ((wc >> 6) == nh) {
#pragma unroll
        for (int j = 0; j < 4; ++j) {
          int col = j * 16 + fr;  // dh_l 0..63
          float bias = bv[(n0 + nh * 64 + col) & 1023];
#pragma unroll
          for (int i = 0; i < 4; ++i) {
            int sl = wr + i * 16 + fq * 4;
            ushort4 pk;
            pk.x = f2b(acc[i][j][0] + bias);
            pk.y = f2b(acc[i][j][1] + bias);
            pk.z = f2b(acc[i][j][2] + bias);
            pk.w = f2b(acc[i][j][3] + bias);
            *(uint2*)&Es[col * 136 + sl] = *(uint2*)&pk;
          }
        }
      }
      __syncthreads();
      int h = ((n0 + nh * 64) & 1023) >> 6;
#pragma unroll
      for (int it = 0; it < 4; ++it) {
        int dh = it * 16 + (t >> 4);
        int ck = (t & 15) * 8;
        uint4 vv = *(uint4*)&Es[dh * 136 + ck];
        *(uint4*)&vtb[(size_t)((bidx * 16 + h) * 64 + dh) * 2048 + s0 + ck] = vv;
      }
      __syncthreads();
    }
  } else {
    unsigned short* dst = (which == 0) ? qb : kb;
    const float* bias_p = (which == 0) ? bq : bk;
    float scale = (which == 0) ? 0.1803368801111204f : 1.0f;
#pragma unroll
    for (int nh = 0; nh < 2; ++nh) {
      if ((wc >> 6) == nh) {
#pragma unroll
        for (int j = 0; j < 4; ++j) {
          int col = j * 16 + fr;
          float bias = bias_p[(n0 + nh * 64 + col) & 1023];
#pragma unroll
          for (int i = 0; i < 4; ++i)
#pragma unroll
            for (int r = 0; r < 4; ++r) {
              int sl = wr + i * 16 + fq * 4 + r;
              Es[sl * 72 + col] = f2b((acc[i][j][r] + bias) * scale);
            }
        }
      }
      __syncthreads();
      int h = ((n0 + nh * 64) & 1023) >> 6;
#pragma unroll
      for (int it = 0; it < 4; ++it) {
        int sl = it * 32 + (t >> 3);
        int ck = (t & 7) * 8;
        uint4 vv = *(uint4*)&Es[sl * 72 + ck];
        *(uint4*)&dst[(size_t)((bidx * 16 + h) * 2048 + s0 + sl) * 64 + ck] = vv;
      }
      __syncthreads();
    }
  }
}

// ---------------- flash attention (round-1 version, best measured: 53.6us) ----------------
__global__ __launch_bounds__(256, 2) void attn_kernel(const unsigned short* __restrict__ qb,
                                                      const unsigned short* __restrict__ kb,
                                                      const unsigned short* __restrict__ vtb,
                                                      unsigned short* __restrict__ attn) {
  __shared__ unsigned short Ks[2 * 4096];
  __shared__ unsigned short Vs[2 * 4096];
  __shared__ unsigned short Ps[4 * 2048];
  const int t = threadIdx.x, lane = t & 63, w = t >> 6;
  const int fr = lane & 15, fq = lane >> 4;
  const int rid = blockIdx.y * 16 + blockIdx.x;
  const int bh = (rid & 7) + ((rid >> 7) << 3);
  const int q0 = ((rid >> 3) & 15) * 128;
  const int ksel = (fq ^ ((fr >> 1) & 3)) * 8;
  const unsigned short* qg = qb + (size_t)bh * 2048 * 64;
  const unsigned short* kg0 = kb + (size_t)bh * 2048 * 64;
  const unsigned short* vg0 = vtb + (size_t)bh * 64 * 2048;

  bf16x8 qf[2][2];
#pragma unroll
  for (int nb = 0; nb < 2; ++nb)
#pragma unroll
    for (int kk = 0; kk < 2; ++kk)
      qf[nb][kk] = *(const bf16x8*)(qg + (size_t)(q0 + w * 32 + nb * 16 + fr) * 64 + kk * 32 + fq * 8);

  bf16x8 ones;
#pragma unroll
  for (int i = 0; i < 8; ++i) ones[i] = (short)0x3F80;

  f32x4 oacc[2][4] = {};
  f32x4 lacc[2] = {};
  unsigned short* Pw = Ps + w * 2048;

  {
#pragma unroll
    for (int rep = 0; rep < 2; ++rep) {
      int c = t + rep * 256;
      int kk = c >> 8, row = (c >> 2) & 63, cc = c & 3;
      int cs = cc ^ ((row >> 1) & 3);  // pre-swizzle global source chunk
      gld16(kg0 + row * 64 + kk * 32 + cs * 8, (void*)(Ks + c * 8));
      gld16(vg0 + (size_t)row * 2048 + kk * 32 + cs * 8, (void*)(Vs + c * 8));
    }
  }

  for (int kt = 0; kt < 32; ++kt) {
    int buf = kt & 1;
    __syncthreads();
    if (kt + 1 < 32) {
      const unsigned short* kg = kg0 + (size_t)(kt + 1) * 4096;
      const unsigned short* vg = vg0 + (kt + 1) * 64;
      int lb = (buf ^ 1) * 4096;
#pragma unroll
      for (int rep = 0; rep < 2; ++rep) {
        int c = t + rep * 256;
        int kk = c >> 8, row = (c >> 2) & 63, cc = c & 3;
        int cs = cc ^ ((row >> 1) & 3);
        gld16(kg + row * 64 + kk * 32 + cs * 8, (void*)(Ks + lb + c * 8));
        gld16(vg + (size_t)row * 2048 + kk * 32 + cs * 8, (void*)(Vs + lb + c * 8));
      }
    }
    const unsigned short* Kb = Ks + buf * 4096;
    const unsigned short* Vb = Vs + buf * 4096;
    f32x4 sacc[4][2] = {};
#pragma unroll
    for (int kk = 0; kk < 2; ++kk) {
      bf16x8 kf[4];
#pragma unroll
      for (int m = 0; m < 4; ++m) kf[m] = *(const bf16x8*)&Kb[kk * 2048 + (m * 16 + fr) * 32 + ksel];
      __builtin_amdgcn_s_setprio(1);
#pragma unroll
      for (int m = 0; m < 4; ++m)
#pragma unroll
        for (int nb = 0; nb < 2; ++nb)
          sacc[m][nb] = __builtin_amdgcn_mfma_f32_16x16x32_bf16(kf[m], qf[nb][kk], sacc[m][nb], 0, 0, 0);
      __builtin_amdgcn_s_setprio(0);
    }
#pragma unroll
    for (int m = 0; m < 4; ++m)
#pragma unroll
      for (int nb = 0; nb < 2; ++nb) {
        int qw = nb * 16 + fr;
        int G = (m * 2 + (fq >> 1)) ^ (qw & 7);
        ushort4 pk;
        pk.x = f2b(__builtin_amdgcn_exp2f(sacc[m][nb][0]));
        pk.y = f2b(__builtin_amdgcn_exp2f(sacc[m][nb][1]));
        pk.z = f2b(__builtin_amdgcn_exp2f(sacc[m][nb][2]));
        pk.w = f2b(__builtin_amdgcn_exp2f(sacc[m][nb][3]));
        *(uint2*)&Pw[qw * 64 + G * 8 + (fq & 1) * 4] = *(uint2*)&pk;
      }
#pragma unroll
    for (int kk = 0; kk < 2; ++kk) {
      bf16x8 pf[2];
#pragma unroll
      for (int mb = 0; mb < 2; ++mb) {
        int qw = mb * 16 + fr;
        int G = (kk * 4 + fq) ^ (qw & 7);
        pf[mb] = *(const bf16x8*)&Pw[qw * 64 + G * 8];
      }
      __builtin_amdgcn_s_setprio(1);
#pragma unroll
      for (int n = 0; n < 4; ++n) {
        bf16x8 vf = *(const bf16x8*)&Vb[kk * 2048 + (n * 16 + fr) * 32 + ksel];
#pragma unroll
        for (int mb = 0; mb < 2; ++mb)
          oacc[mb][n] = __builtin_amdgcn_mfma_f32_16x16x32_bf16(pf[mb], vf, oacc[mb][n], 0, 0, 0);
      }
#pragma unroll
      for (int mb = 0; mb < 2; ++mb)
        lacc[mb] = __builtin_amdgcn_mfma_f32_16x16x32_bf16(pf[mb], ones, lacc[mb], 0, 0, 0);
      __builtin_amdgcn_s_setprio(0);
    }
  }
  int bidx = bh >> 4, h = bh & 15;
#pragma unroll
  for (int mb = 0; mb < 2; ++mb)
#pragma unroll
    for (int r = 0; r < 4; ++r) {
      float inv = 1.f / lacc[mb][r];
      int s = q0 + w * 32 + mb * 16 + fq * 4 + r;
      size_t base = (size_t)(bidx * 2048 + s) * 1024 + h * 64;
#pragma unroll
      for (int n = 0; n < 4; ++n) attn[base + n * 16 + fr] = f2b(oacc[mb][n][r] * inv);
    }
}

// ---------------- output projection ----------------
// Round-7: 128x64 tiles, grid (32,16)=512 blocks -> 2 blocks/CU so the
// stage->barrier drain of one block overlaps compute of the other (the
// mechanism qkv already benefits from at 3/CU; at the old grid=256 this
// kernel had zero co-residency and exposed the full load latency each of
// its 32 K-steps).
__global__ __launch_bounds__(256) void gemm_out(const unsigned short* __restrict__ Ab,
                                                const unsigned short* __restrict__ Bt,
                                                const float* __restrict__ bo,
                                                float* __restrict__ out) {
  __shared__ unsigned short As[128 * 32];
  __shared__ unsigned short Bs[64 * 32];
  const int t = threadIdx.x;
  const int lane = t & 63, wave = t >> 6;
  const int m0 = blockIdx.x * 128, n0 = blockIdx.y * 64;
  const int wr = (wave >> 1) * 64, wc = (wave & 1) * 32;
  const int fr = lane & 15, fq = lane >> 4;
  f32x4 acc[4][2] = {};
  for (int kt = 0; kt < 32; ++kt) {
    const unsigned short* Ag = Ab + (size_t)m0 * 1024 + kt * 32;
    const unsigned short* Bg = Bt + (size_t)n0 * 1024 + kt * 32;
#pragma unroll
    for (int rep = 0; rep < 2; ++rep) {
      int c = t + rep * 256;
      int row = c >> 2, col = (c & 3) * 8;
      gld16(Ag + (size_t)row * 1024 + col, (void*)(As + c * 8));
    }
    {
      int c = t;
      int row = c >> 2, col = (c & 3) * 8;
      gld16(Bg + (size_t)row * 1024 + col, (void*)(Bs + c * 8));
    }
    __syncthreads();
    bf16x8 a[4], b[2];
#pragma unroll
    for (int i = 0; i < 4; ++i) a[i] = *(const bf16x8*)&As[(wr + i * 16 + fr) * 32 + fq * 8];
#pragma unroll
    for (int j = 0; j < 2; ++j) b[j] = *(const bf16x8*)&Bs[(wc + j * 16 + fr) * 32 + fq * 8];
#pragma unroll
    for (int i = 0; i < 4; ++i)
#pragma unroll
      for (int j = 0; j < 2; ++j)
        acc[i][j] = __builtin_amdgcn_mfma_f32_16x16x32_bf16(a[i], b[j], acc[i][j], 0, 0, 0);
    __syncthreads();
  }
#pragma unroll
  for (int j = 0; j < 2; ++j) {
    int gn = n0 + wc + j * 16 + fr;
    float bias = bo[gn];
#pragma unroll
    for (int i = 0; i < 4; ++i)
#pragma unroll
      for (int r = 0; r < 4; ++r) {
        int gm = m0 + wr + i * 16 + fq * 4 + r;
        out[(size_t)gm * 1024 + gn] = acc[i][j][r] + bias;
      }
  }
}

extern "C" void kernel_launch(void* const* d_in, const int* in_sizes, int n_in,
                              void* d_out, int out_size, void* d_ws, size_t ws_size,
                              hipStream_t stream) {
  const float* x = (const float*)d_in[0];
  const float* Wq = (const float*)d_in[1];
  const float* bq = (const float*)d_in[2];
  const float* Wk = (const float*)d_in[3];
  const float* bk = (const float*)d_in[4];
  const float* Wv = (const float*)d_in[5];
  const float* bv = (const float*)d_in[6];
  const float* Wo = (const float*)d_in[7];
  const float* bo = (const float*)d_in[8];
  float* out = (float*)d_out;

  unsigned short* ws = (unsigned short*)d_ws;
  const size_t MI = (size_t)1024 * 1024;
  unsigned short* xb = ws;
  unsigned short* wt = ws + 4 * MI;
  unsigned short* qb = wt + 4 * MI;
  unsigned short* kb = qb + 4 * MI;
  unsigned short* vtb = kb + 4 * MI;
  unsigned short* attn = xb;  // reuse xb after QKV gemm

  prep_kernel<<<5120, 256, 0, stream>>>(x, Wq, Wk, Wv, Wo, xb, wt);
  gemm_qkv<<<dim3(32, 24), 256, 0, stream>>>(xb, wt, bq, bk, bv, qb, kb, vtb);
  attn_kernel<<<dim3(16, 32), 256, 0, stream>>>(qb, kb, vtb, attn);
  gemm_out<<<dim3(32, 16), 256, 0, stream>>>(attn, wt + 3 * MI, bo, out);
}